// Round 12
// baseline (142.969 us; speedup 1.0000x reference)
//
#include <hip/hip_runtime.h>

// GraphSAGE mean aggregator on MI355X.
// out = fb@W_self + mean(fb[src] by dst)@W_neigh + biases   (fb = bf16(feat))
// R2-R10: CSR gather-side reduction, parallel scan, bf16 MFMA K=256, predicated
// 8-batch gather, natural-width CSR build, hn-before-mm dataflow.
// R12: gather fused INTO mm (mmgather): per-128-row block, waves mean-gather
//      their 32 rows into a padded LDS tile (272B rows -> 2-way banks, free),
//      then MFMA reads hn fragments from LDS. Kills the 51MB hn round-trip and
//      overlaps latency-bound gather with memory-bound mm. Weights from global
//      (L2-resident) to keep LDS at 35KB (occupancy for gather TLP).
//      Also: scanb folded into final (redundant per-block boff, R8-proven).

constexpr int N_NODES = 100000;
constexpr int N_EDGES = 640000;
constexpr int D = 128;

constexpr int SCAN_ELEMS_PER_BLOCK = 1024;   // 256 threads x 4
constexpr int SCAN_NBLOCKS = (N_NODES + SCAN_ELEMS_PER_BLOCK - 1) / SCAN_ELEMS_PER_BLOCK; // 98

typedef __attribute__((ext_vector_type(8))) short bf16x8;
typedef __attribute__((ext_vector_type(4))) float f32x4;

__device__ __forceinline__ unsigned short f2bf(float f) {
    unsigned int u = __float_as_uint(f);
    unsigned int r = u + 0x7FFFu + ((u >> 16) & 1u);   // round-to-nearest-even
    return (unsigned short)(r >> 16);
}

// ---------------- zero deg (int4-wide, full-width grid) ----------------
__global__ __launch_bounds__(256) void zero_deg_kernel(int4* __restrict__ deg4) {
    int i = blockIdx.x * 256 + threadIdx.x;
    if (i < N_NODES / 4) deg4[i] = int4{0, 0, 0, 0};
}

// ------- prepass: deg atomics + weight packing + feat->bf16 (independent) -----
// wp flat index i = (((m*4+ks)*4+h)*128 + c)*8 + r  holds  bf16(W_m[ks*32+h*8+r][c])
// Same (h,r)->k map as the A-fragment build in mmgather (shared k-permutation).
__global__ void prepass_kernel(const int* __restrict__ dst, int* __restrict__ deg,
                               const float* __restrict__ Ws, const float* __restrict__ Wn,
                               unsigned short* __restrict__ wp,
                               const float* __restrict__ feat, unsigned short* __restrict__ fb) {
    const int gid = blockIdx.x * blockDim.x + threadIdx.x;   // 640K threads
    if (gid < N_EDGES) atomicAdd(&deg[dst[gid]], 1);
    if (gid < 2 * D * D) {
        int i = gid;
        int r  = i & 7;
        int c  = (i >> 3) & 127;
        int h  = (i >> 10) & 3;
        int ks = (i >> 12) & 3;
        int m  = i >> 14;
        const float* W = m ? Wn : Ws;
        int k = ks * 32 + h * 8 + r;
        wp[i] = f2bf(W[k * D + c]);
    }
    const int total4 = N_NODES * D / 4;
    for (int i = gid; i < total4; i += N_EDGES) {
        float4 v = ((const float4*)feat)[i];
        ushort4 o;
        o.x = f2bf(v.x); o.y = f2bf(v.y); o.z = f2bf(v.z); o.w = f2bf(v.w);
        ((ushort4*)fb)[i] = o;
    }
}

// ---------------- scan: partial sums, then final (fused boff + fill-prep) -----

__global__ __launch_bounds__(256) void partial_kernel(const int* __restrict__ deg,
                                                      int* __restrict__ bsum) {
    __shared__ int wsum[4];
    const int tid = threadIdx.x;
    const int base = (blockIdx.x * 256 + tid) * 4;
    int s = 0;
    #pragma unroll
    for (int j = 0; j < 4; j++) {
        int idx = base + j;
        if (idx < N_NODES) s += deg[idx];
    }
    for (int off = 32; off > 0; off >>= 1) s += __shfl_down(s, off, 64);
    if ((tid & 63) == 0) wsum[tid >> 6] = s;
    __syncthreads();
    if (tid == 0) bsum[blockIdx.x] = wsum[0] + wsum[1] + wsum[2] + wsum[3];
}

// final: each block redundantly computes its exclusive block offset from bsum
// (R8 phase-2 pattern), then intra-block scan -> rowptr, cursor.
__global__ __launch_bounds__(256) void final_kernel(const int* __restrict__ deg,
                                                    const int* __restrict__ bsum,
                                                    int* __restrict__ rowptr,
                                                    int* __restrict__ cursor) {
    __shared__ int wsum[4];
    const int tid = threadIdx.x;
    const int lane = tid & 63;
    const int wave = tid >> 6;
    const int base = (blockIdx.x * 256 + tid) * 4;

    int local[4];
    int tsum = 0;
    #pragma unroll
    for (int j = 0; j < 4; j++) {
        int idx = base + j;
        local[j] = (idx < N_NODES) ? deg[idx] : 0;
        tsum += local[j];
    }

    // block offset: sum of bsum[0..blockIdx.x)
    int v = (tid < blockIdx.x) ? bsum[tid] : 0;     // blockIdx.x < 98 <= 256
    for (int off = 32; off > 0; off >>= 1) v += __shfl_down(v, off, 64);
    if (lane == 0) wsum[wave] = v;
    __syncthreads();
    const int boff = wsum[0] + wsum[1] + wsum[2] + wsum[3];
    __syncthreads();

    int incl = tsum;
    for (int off = 1; off < 64; off <<= 1) {
        int u = __shfl_up(incl, off, 64);
        if (lane >= off) incl += u;
    }
    if (lane == 63) wsum[wave] = incl;
    __syncthreads();
    int woff = 0;
    for (int w = 0; w < 4; w++) woff += (w < wave) ? wsum[w] : 0;

    int run = boff + woff + (incl - tsum);
    #pragma unroll
    for (int j = 0; j < 4; j++) {
        int idx = base + j;
        if (idx < N_NODES) {
            rowptr[idx] = run;
            cursor[idx] = run;
            run += local[j];
        }
    }
    if (blockIdx.x == 0 && tid == 0) rowptr[N_NODES] = N_EDGES;
}

__global__ void fill_kernel(const int* __restrict__ src, const int* __restrict__ dst,
                            int* __restrict__ cursor, int* __restrict__ csr_src) {
    int e = blockIdx.x * blockDim.x + threadIdx.x;
    if (e < N_EDGES) {
        int pos = atomicAdd(&cursor[dst[e]], 1);
        csr_src[pos] = src[e];
    }
}

// -------- fused gather + matmul: out = fb@Ws + mean(fb[src])@Wn + bias --------
// Block = 256 thr = 4 waves, 128 rows. Phase 1: wave w mean-gathers nodes
// [row_base+w*32, +32) into LDS tile (row-padded to 272B: 2-way banks, free).
// Phase 2: K=256 MFMA; fb fragments from global, hn fragments from LDS,
// W fragments from global wp (L2-resident, 65KB).
__global__ __launch_bounds__(256) void mmgather_kernel(
    const unsigned short* __restrict__ fb, const int* __restrict__ csr_src,
    const int* __restrict__ rowptr, const unsigned short* __restrict__ wp,
    const float* __restrict__ b_self, const float* __restrict__ b_neigh,
    float* __restrict__ out)
{
    __shared__ unsigned int lhn[128][68];   // 68 uints = 256B data + 16B pad

    const int tid = threadIdx.x;
    const int wave = tid >> 6, lane = tid & 63;
    const int row_base = blockIdx.x * 128;

    // ---- Phase 1: gather-mean into LDS ----
    for (int i = 0; i < 32; i++) {
        const int n = row_base + wave * 32 + i;
        float ax = 0.f, ay = 0.f;
        float sc = 0.f;
        if (n < N_NODES) {
            const int e0 = rowptr[n];
            const int e1 = rowptr[n + 1];
            for (int base = e0; base < e1; base += 8) {
                int sidx[8];
                #pragma unroll
                for (int j = 0; j < 8; j++) {
                    int ee = base + j;
                    ee = (ee < e1) ? ee : (e1 - 1);      // clamp, no branch
                    sidx[j] = csr_src[ee];
                }
                unsigned int v[8];
                #pragma unroll
                for (int j = 0; j < 8; j++)
                    v[j] = ((const unsigned int*)(fb + (size_t)sidx[j] * D))[lane];
                #pragma unroll
                for (int j = 0; j < 8; j++) {
                    const float w = (base + j < e1) ? 1.0f : 0.0f;
                    ax = fmaf(w, __uint_as_float(v[j] << 16), ax);
                    ay = fmaf(w, __uint_as_float(v[j] & 0xFFFF0000u), ay);
                }
            }
            sc = 1.0f / (float)max(e1 - e0, 1);
        }
        lhn[wave * 32 + i][lane] =
            ((unsigned int)f2bf(ay * sc) << 16) | (unsigned int)f2bf(ax * sc);
    }
    __syncthreads();

    // ---- Phase 2: MFMA ----
    const int h = lane >> 4, c = lane & 15;

    // fb A-fragments from global: rows row_base + wave*32 + ti*16 + c
    bf16x8 a0[2][4];
    #pragma unroll
    for (int ti = 0; ti < 2; ti++) {
        int row = row_base + wave * 32 + ti * 16 + c;
        int rowc = min(row, N_NODES - 1);            // clamp; stores are guarded
        const bf16x8* f0 = (const bf16x8*)(fb + (size_t)rowc * D);
        #pragma unroll
        for (int ks = 0; ks < 4; ks++) a0[ti][ks] = f0[ks * 4 + h];
    }
    // hn A-fragments from LDS: local row wave*32 + ti*16 + c, bytes ks*64+h*16
    bf16x8 a1[2][4];
    #pragma unroll
    for (int ti = 0; ti < 2; ti++) {
        const int lr = wave * 32 + ti * 16 + c;
        #pragma unroll
        for (int ks = 0; ks < 4; ks++)
            a1[ti][ks] = *(const bf16x8*)&lhn[lr][ks * 16 + h * 4];
    }

    for (int ct = 0; ct < 8; ct++) {
        f32x4 acc[2];
        #pragma unroll
        for (int ti = 0; ti < 2; ti++) acc[ti] = f32x4{0.f, 0.f, 0.f, 0.f};

        #pragma unroll
        for (int ks = 0; ks < 4; ks++) {
            bf16x8 b0 = ((const bf16x8*)wp)[((0 * 4 + ks) * 4 + h) * 128 + ct * 16 + c];
            bf16x8 b1 = ((const bf16x8*)wp)[((1 * 4 + ks) * 4 + h) * 128 + ct * 16 + c];
            #pragma unroll
            for (int ti = 0; ti < 2; ti++) {
                acc[ti] = __builtin_amdgcn_mfma_f32_16x16x32_bf16(a0[ti][ks], b0, acc[ti], 0, 0, 0);
                acc[ti] = __builtin_amdgcn_mfma_f32_16x16x32_bf16(a1[ti][ks], b1, acc[ti], 0, 0, 0);
            }
        }

        const int col = ct * 16 + c;
        const float bias = b_self[col] + b_neigh[col];
        #pragma unroll
        for (int ti = 0; ti < 2; ti++) {
            int tile_row = row_base + wave * 32 + ti * 16;
            if (tile_row < N_NODES) {                // N%16==0: tile guard exact
                #pragma unroll
                for (int q = 0; q < 4; q++) {
                    int row = tile_row + h * 4 + q;  // C/D: row=(lane>>4)*4+reg
                    out[(size_t)row * D + col] = acc[ti][q] + bias;
                }
            }
        }
    }
}

extern "C" void kernel_launch(void* const* d_in, const int* in_sizes, int n_in,
                              void* d_out, int out_size, void* d_ws, size_t ws_size,
                              hipStream_t stream) {
    const float* feat    = (const float*)d_in[0];
    const int*   src     = (const int*)d_in[1];
    const int*   dst     = (const int*)d_in[2];
    const float* W_self  = (const float*)d_in[3];
    const float* b_self  = (const float*)d_in[4];
    const float* W_neigh = (const float*)d_in[5];
    const float* b_neigh = (const float*)d_in[6];
    float* out = (float*)d_out;

    // ws layout: fb [N*D bf16] | wp [2*D*D bf16] | deg [N] | rowptr [N+1] |
    //            cursor [N] | csr_src [E] | bsum [98]
    unsigned short* fb = (unsigned short*)d_ws;
    unsigned short* wp = fb + (size_t)N_NODES * D;
    int*   deg     = (int*)(wp + 2 * D * D);
    int*   rowptr  = deg + N_NODES;
    int*   cursor  = rowptr + (N_NODES + 1);
    int*   csr_src = cursor + N_NODES;
    int*   bsum    = csr_src + N_EDGES;

    zero_deg_kernel<<<(N_NODES / 4 + 255) / 256, 256, 0, stream>>>((int4*)deg);

    prepass_kernel<<<(N_EDGES + 255) / 256, 256, 0, stream>>>(dst, deg, W_self, W_neigh,
                                                              wp, feat, fb);

    partial_kernel<<<SCAN_NBLOCKS, 256, 0, stream>>>(deg, bsum);
    final_kernel<<<SCAN_NBLOCKS, 256, 0, stream>>>(deg, bsum, rowptr, cursor);

    fill_kernel<<<(N_EDGES + 255) / 256, 256, 0, stream>>>(src, dst, cursor, csr_src);

    mmgather_kernel<<<(N_NODES + 127) / 128, 256, 0, stream>>>(fb, csr_src, rowptr, wp,
                                                               b_self, b_neigh, out);
}

// Round 13
// 139.078 us; speedup vs baseline: 1.0280x; 1.0280x over previous
//
#include <hip/hip_runtime.h>

// GraphSAGE mean aggregator on MI355X.
// hn = segment_mean(fb[src], dst);  out = fb@W_self + hn@W_neigh + biases
// R2-R11: CSR gather-side reduction, parallel scan, bf16 MFMA K=256 (fb|hn),
//         predicated 8-batch gather, hn-before-mm dataflow.
// R12 (reverted): gather-in-mm fusion serialized gather (32 nodes/wave, 28% occ).
// R13: mmfused reads weights from global (no LDS -> 2x blocks/CU for a
//      memory-bound kernel); scan = ONE kernel (98 blocks + grid barrier,
//      scan-only work — R8's failure was fill-in-narrow-grid, not scan);
//      6 launches total; nt stores on out.

constexpr int N_NODES = 100000;
constexpr int N_EDGES = 640000;
constexpr int D = 128;

constexpr int SCAN_NBLOCKS = 98;   // 98 x 1024 elems covers 100000

typedef __attribute__((ext_vector_type(8))) short bf16x8;
typedef __attribute__((ext_vector_type(4))) float f32x4;

__device__ __forceinline__ unsigned short f2bf(float f) {
    unsigned int u = __float_as_uint(f);
    unsigned int r = u + 0x7FFFu + ((u >> 16) & 1u);   // round-to-nearest-even
    return (unsigned short)(r >> 16);
}

// ---------------- zero deg (int4-wide, full-width grid) ----------------
__global__ __launch_bounds__(256) void zero_deg_kernel(int4* __restrict__ deg4) {
    int i = blockIdx.x * 256 + threadIdx.x;
    if (i < N_NODES / 4) deg4[i] = int4{0, 0, 0, 0};
}

// ------- prepass: deg atomics + weight packing + feat->bf16 + ctr zero -------
// wp flat index i = (((m*4+ks)*4+h)*128 + c)*8 + r  holds  bf16(W_m[ks*32+h*8+r][c])
// Same (h,r)->k map as the A-fragment build in mmfused (shared k-permutation).
__global__ void prepass_kernel(const int* __restrict__ dst, int* __restrict__ deg,
                               const float* __restrict__ Ws, const float* __restrict__ Wn,
                               unsigned short* __restrict__ wp,
                               const float* __restrict__ feat, unsigned short* __restrict__ fb,
                               int* __restrict__ ctr) {
    const int gid = blockIdx.x * blockDim.x + threadIdx.x;   // 640K threads
    if (gid == 0) ctr[0] = 0;                 // scan grid-barrier counter
    if (gid < N_EDGES) atomicAdd(&deg[dst[gid]], 1);
    if (gid < 2 * D * D) {
        int i = gid;
        int r  = i & 7;
        int c  = (i >> 3) & 127;
        int h  = (i >> 10) & 3;
        int ks = (i >> 12) & 3;
        int m  = i >> 14;
        const float* W = m ? Wn : Ws;
        int k = ks * 32 + h * 8 + r;
        wp[i] = f2bf(W[k * D + c]);
    }
    const int total4 = N_NODES * D / 4;
    for (int i = gid; i < total4; i += N_EDGES) {
        float4 v = ((const float4*)feat)[i];
        ushort4 o;
        o.x = f2bf(v.x); o.y = f2bf(v.y); o.z = f2bf(v.z); o.w = f2bf(v.w);
        ((ushort4*)fb)[i] = o;
    }
}

// ---------------- fused scan: partial sums + grid barrier + rowptr/cursor ----
// 98 blocks (all co-resident on 256 CUs), scan-only work. ctr zeroed by prepass.
__global__ __launch_bounds__(256) void scan_kernel(const int* __restrict__ deg,
                                                   int* __restrict__ rowptr,
                                                   int* __restrict__ cursor,
                                                   int* __restrict__ bsum,
                                                   int* __restrict__ ctr) {
    __shared__ int wsum[4];
    const int tid = threadIdx.x;
    const int lane = tid & 63;
    const int wave = tid >> 6;
    const int base = (blockIdx.x * 256 + tid) * 4;

    int local[4];
    int tsum = 0;
    #pragma unroll
    for (int j = 0; j < 4; j++) {
        int idx = base + j;
        local[j] = (idx < N_NODES) ? deg[idx] : 0;
        tsum += local[j];
    }
    // Phase 1: publish per-block sum.
    {
        int s = tsum;
        for (int off = 32; off > 0; off >>= 1) s += __shfl_down(s, off, 64);
        if (lane == 0) wsum[wave] = s;
        __syncthreads();
        if (tid == 0) bsum[blockIdx.x] = wsum[0] + wsum[1] + wsum[2] + wsum[3];
    }
    // Grid barrier.
    __syncthreads();
    if (tid == 0) {
        __threadfence();
        __hip_atomic_fetch_add(ctr, 1, __ATOMIC_ACQ_REL, __HIP_MEMORY_SCOPE_AGENT);
        while (__hip_atomic_load(ctr, __ATOMIC_ACQUIRE, __HIP_MEMORY_SCOPE_AGENT)
               < SCAN_NBLOCKS) {}
    }
    __syncthreads();

    // Phase 2: block offset (redundant per block), intra-block scan, write.
    int v = (tid < blockIdx.x) ? bsum[tid] : 0;     // blockIdx.x < 98 <= 256
    for (int off = 32; off > 0; off >>= 1) v += __shfl_down(v, off, 64);
    if (lane == 0) wsum[wave] = v;
    __syncthreads();
    const int boff = wsum[0] + wsum[1] + wsum[2] + wsum[3];
    __syncthreads();

    int incl = tsum;
    for (int off = 1; off < 64; off <<= 1) {
        int u = __shfl_up(incl, off, 64);
        if (lane >= off) incl += u;
    }
    if (lane == 63) wsum[wave] = incl;
    __syncthreads();
    int woff = 0;
    for (int w = 0; w < 4; w++) woff += (w < wave) ? wsum[w] : 0;

    int run = boff + woff + (incl - tsum);
    #pragma unroll
    for (int j = 0; j < 4; j++) {
        int idx = base + j;
        if (idx < N_NODES) {
            rowptr[idx] = run;
            cursor[idx] = run;
            run += local[j];
        }
    }
    if (blockIdx.x == 0 && tid == 0) rowptr[N_NODES] = N_EDGES;
}

__global__ void fill_kernel(const int* __restrict__ src, const int* __restrict__ dst,
                            int* __restrict__ cursor, int* __restrict__ csr_src) {
    int e = blockIdx.x * blockDim.x + threadIdx.x;
    if (e < N_EDGES) {
        int pos = atomicAdd(&cursor[dst[e]], 1);
        csr_src[pos] = src[e];
    }
}

// ---------------- gather: mean(fb[src]) -> hn (bf16, written once) -----------
// One wave per node; branch-free predicated 8-batches; lane packs 2 bf16.
__global__ __launch_bounds__(256) void gather_kernel(
    const unsigned short* __restrict__ fb, const int* __restrict__ csr_src,
    const int* __restrict__ rowptr, unsigned short* __restrict__ hn)
{
    const int lane = threadIdx.x & 63;
    const int n = (blockIdx.x * blockDim.x + threadIdx.x) >> 6;
    if (n >= N_NODES) return;

    const int e0 = rowptr[n];
    const int e1 = rowptr[n + 1];

    float ax = 0.f, ay = 0.f;
    for (int base = e0; base < e1; base += 8) {
        int sidx[8];
        #pragma unroll
        for (int j = 0; j < 8; j++) {
            int ee = base + j;
            ee = (ee < e1) ? ee : (e1 - 1);          // clamp, no branch
            sidx[j] = csr_src[ee];
        }
        unsigned int v[8];
        #pragma unroll
        for (int j = 0; j < 8; j++)
            v[j] = ((const unsigned int*)(fb + (size_t)sidx[j] * D))[lane];
        #pragma unroll
        for (int j = 0; j < 8; j++) {
            const float w = (base + j < e1) ? 1.0f : 0.0f;
            ax = fmaf(w, __uint_as_float(v[j] << 16), ax);
            ay = fmaf(w, __uint_as_float(v[j] & 0xFFFF0000u), ay);
        }
    }
    const float sc = 1.0f / (float)max(e1 - e0, 1);
    const unsigned int packed =
        ((unsigned int)f2bf(ay * sc) << 16) | (unsigned int)f2bf(ax * sc);
    ((unsigned int*)(hn + (size_t)n * D))[lane] = packed;   // zero-deg -> 0
}

// ---------------- single K=256 matmul: out = fb@Ws + hn@Wn + bias ------------
// Block = 256 thr = 4 waves, 128 rows. No LDS: W fragments read from global wp
// (64KB, L2/L1-resident broadcast) -> blocks/CU not LDS-capped, 2x TLP.
__global__ __launch_bounds__(256) void mmfused_kernel(
    const unsigned short* __restrict__ fb, const unsigned short* __restrict__ hn,
    const unsigned short* __restrict__ wp,
    const float* __restrict__ b_self, const float* __restrict__ b_neigh,
    float* __restrict__ out)
{
    const int tid = threadIdx.x;
    const int wave = tid >> 6, lane = tid & 63;
    const int h = lane >> 4, c = lane & 15;
    const int row_base = blockIdx.x * 128 + wave * 32;

    // A fragments: a[m][ti][ks], m=0 -> fb, m=1 -> hn (both bf16 row-major).
    bf16x8 a[2][2][4];
    #pragma unroll
    for (int ti = 0; ti < 2; ti++) {
        int row = row_base + ti * 16 + c;
        int rowc = min(row, N_NODES - 1);             // clamp; stores are guarded
        const bf16x8* f0 = (const bf16x8*)(fb + (size_t)rowc * D);
        const bf16x8* f1 = (const bf16x8*)(hn + (size_t)rowc * D);
        #pragma unroll
        for (int ks = 0; ks < 4; ks++) {
            a[0][ti][ks] = f0[ks * 4 + h];
            a[1][ti][ks] = f1[ks * 4 + h];
        }
    }

    const bf16x8* wpv = (const bf16x8*)wp;
    for (int ct = 0; ct < 8; ct++) {
        f32x4 acc[2];
        #pragma unroll
        for (int ti = 0; ti < 2; ti++) acc[ti] = f32x4{0.f, 0.f, 0.f, 0.f};

        #pragma unroll
        for (int m = 0; m < 2; m++) {
            bf16x8 b[4];
            #pragma unroll
            for (int ks = 0; ks < 4; ks++)
                b[ks] = wpv[((m * 4 + ks) * 4 + h) * 128 + ct * 16 + c];
            #pragma unroll
            for (int ks = 0; ks < 4; ks++)
                #pragma unroll
                for (int ti = 0; ti < 2; ti++)
                    acc[ti] = __builtin_amdgcn_mfma_f32_16x16x32_bf16(a[m][ti][ks], b[ks], acc[ti], 0, 0, 0);
        }

        const int col = ct * 16 + c;
        const float bias = b_self[col] + b_neigh[col];
        #pragma unroll
        for (int ti = 0; ti < 2; ti++) {
            if (row_base + ti * 16 < N_NODES) {       // N%16==0: tile guard exact
                #pragma unroll
                for (int q = 0; q < 4; q++) {
                    int row = row_base + ti * 16 + h * 4 + q;   // C/D: row=(lane>>4)*4+reg
                    __builtin_nontemporal_store(acc[ti][q] + bias,
                                                &out[(size_t)row * D + col]);
                }
            }
        }
    }
}

extern "C" void kernel_launch(void* const* d_in, const int* in_sizes, int n_in,
                              void* d_out, int out_size, void* d_ws, size_t ws_size,
                              hipStream_t stream) {
    const float* feat    = (const float*)d_in[0];
    const int*   src     = (const int*)d_in[1];
    const int*   dst     = (const int*)d_in[2];
    const float* W_self  = (const float*)d_in[3];
    const float* b_self  = (const float*)d_in[4];
    const float* W_neigh = (const float*)d_in[5];
    const float* b_neigh = (const float*)d_in[6];
    float* out = (float*)d_out;

    // ws layout: fb [N*D bf16] | hn [N*D bf16] | wp [2*D*D bf16] | deg [N] |
    //            rowptr [N+1] | cursor [N] | csr_src [E] | bsum [98] | ctr [1]
    unsigned short* fb = (unsigned short*)d_ws;
    unsigned short* hn = fb + (size_t)N_NODES * D;
    unsigned short* wp = hn + (size_t)N_NODES * D;
    int*   deg     = (int*)(wp + 2 * D * D);
    int*   rowptr  = deg + N_NODES;
    int*   cursor  = rowptr + (N_NODES + 1);
    int*   csr_src = cursor + N_NODES;
    int*   bsum    = csr_src + N_EDGES;
    int*   ctr     = bsum + SCAN_NBLOCKS;

    zero_deg_kernel<<<(N_NODES / 4 + 255) / 256, 256, 0, stream>>>((int4*)deg);

    prepass_kernel<<<(N_EDGES + 255) / 256, 256, 0, stream>>>(dst, deg, W_self, W_neigh,
                                                              wp, feat, fb, ctr);

    scan_kernel<<<SCAN_NBLOCKS, 256, 0, stream>>>(deg, rowptr, cursor, bsum, ctr);

    fill_kernel<<<(N_EDGES + 255) / 256, 256, 0, stream>>>(src, dst, cursor, csr_src);

    gather_kernel<<<25000, 256, 0, stream>>>(fb, csr_src, rowptr, hn);

    mmfused_kernel<<<(N_NODES + 127) / 128, 256, 0, stream>>>(fb, hn, wp, b_self, b_neigh, out);
}